// Round 13
// baseline (231.925 us; speedup 1.0000x reference)
//
#include <hip/hip_runtime.h>
#include <hip/hip_bf16.h>
#include <math.h>

#define N_   16
#define CIN  16
#define D_   32
#define H_   64
#define W_   64
#define COUT 32

#define DHW_ (D_ * H_ * W_)
#define HW_  (H_ * W_)

using frag  = __attribute__((ext_vector_type(8))) short;   // 8 bf16 = 4 VGPRs
using v16f  = __attribute__((ext_vector_type(16))) float;  // MFMA 32x32 accum

static __device__ __forceinline__ unsigned short f2bf(float f) {
  union { float f; unsigned u; } a; a.f = f;
  unsigned u = a.u;
  unsigned r = (u + 0x7fffu + ((u >> 16) & 1u)) >> 16;   // RNE
  return (unsigned short)r;
}
// Packed f32x2 -> bf16x2 (RNE), single HW instruction.
static __device__ __forceinline__ unsigned pack2(float lo, float hi) {
  unsigned r;
  asm("v_cvt_pk_bf16_f32 %0, %1, %2" : "=v"(r) : "v"(lo), "v"(hi));
  return r;
}

// mod-6 for 0 <= s6 <= 41:  s6 - 6*floor(s6*43/256)  (exact in this range).
static __device__ __forceinline__ int mod6(int s6) {
  return s6 - 6 * ((s6 * 43) >> 8);
}

// Weight prep: wt[tap][ichalf][oc][ic8] (bf16) <- w[oc][ic][tap] (fp32).
// 27*2*32*8 = 13824 elements; grid 54 x 256. (R10-verified.)
__global__ void wprep(const float* __restrict__ w, __hip_bfloat16* __restrict__ wt) {
  int i = blockIdx.x * 256 + threadIdx.x;
  int icl = i & 7, oc = (i >> 3) & 31, half = (i >> 8) & 1, tap = i >> 9;
  int ic = half * 8 + icl;
  wt[i] = __hip_bfloat16(__hip_bfloat16_raw{f2bf(w[(oc * 16 + ic) * 27 + tap])});
}

// Single fused kernel: conv3d(16->32,k3,p1) + bias + maxpool2^3 + LSE(ch) + relu.
// Block = 4 waves. Grid (wt 2, hpt 8, z 32: n=z>>1, dphalf=z&1).
// R12 vs R11 (97us; pipes phase-serialized: matrix 24% + LDS 27% + VALU 16%
// + HBM 14% ~= the wall):
//  - WEIGHTS IN VGPRS: 27 b-frags (108 VGPR) loaded once from wprep'd buffer.
//    Deletes wlds and its 216 ds_reads/dpi (2.6k cyc = 9% of wall) and every
//    b-frag lgkm wait inside the MFMA block. (R10's idea minus its spill/L2
//    failure: register-resident, zero loop loads.)
//  - wlds gone => 6-slot ring @34 wslots = 65280 B fits 2 blocks/CU: back to
//    2x256 geometry (R9). Two independent blocks/CU restore cross-block
//    phase skew (R11's 512-block barrier gated the whole CU) while keeping
//    the ring's ONE barrier/dpi.
// Verification bits: VGPR ~230-256, WRITE_SIZE stays ~1MB (no spill).
__global__ __launch_bounds__(256, 2)
void conv_fused(const float* __restrict__ x,
                const __hip_bfloat16* __restrict__ wt,
                const float* __restrict__ bias,
                float* __restrict__ out) {
  // [6 slot][10 row][2 ichalf][34 wslot][8 ic] = 32640 shorts = 65280 B
  __shared__ __hip_bfloat16 xlds[6 * 10 * 2 * 34 * 8];

  const int tid = threadIdx.x;
  const int lane = tid & 63;
  const int q = tid >> 6;            // wave id 0..3 (h-row group)
  const int m = lane & 31;
  const int hs = lane >> 5;
  const int wtb = blockIdx.x;        // 0..1 (w half)
  const int hpt = blockIdx.y;        // 0..7
  const int n = blockIdx.z >> 1;
  const int dphalf = blockIdx.z & 1;

  // Per-lane bias for the 16 accum rows (row/oc = (r&3)+8*(r>>2)+4*hs).
  float bias_r[16];
  #pragma unroll
  for (int r = 0; r < 16; ++r)
    bias_r[r] = bias[(r & 3) + 8 * (r >> 2) + 4 * hs];

  // ---- weights -> registers: bw[tap] = wt[tap][hs][oc=m][0..7] --------------
  // 27 frags x 4 VGPR = 108 VGPR, static-indexed everywhere (no scratch).
  const __hip_bfloat16* wtl = wt + hs * 256 + m * 8;
  frag bw[27];
  #pragma unroll
  for (int t = 0; t < 27; ++t)
    bw[t] = *(const frag*)&wtl[t * 512];

  const int h0 = 8 * hpt - 1;
  const int w0g = wtb * 32 - 1;
  const float* xn = x + (size_t)n * CIN * DHW_;

  // 8 uniform channel-base pointers -> SGPR pairs.
  const float* xj[8];
  #pragma unroll
  for (int j = 0; j < 8; ++j) xj[j] = xn + (size_t)j * DHW_;

  // ---- per-thread staging descriptors (decode hoisted out of the dpi loop) --
  // Task t = tid + 256k, t in [0,1360): ru = t/68, sub = t%68,
  // s = sub>>1 (w-slot 0..33), half = sub&1 (ic half), go = (ru>=10),
  // rr = ru%10. Only k=5 can be inactive (t>=1360 <=> tid>=80).
  int goffw[6];   // global word offset, excluding the g-plane term
  int ldsoB[6];   // LDS byte offset within one plane slot
  int go6[6];     // plane offset within the staged pair (0/1)
  bool vhw6[6];   // active && h,w in bounds (g checked per call)
  #pragma unroll
  for (int k = 0; k < 6; ++k) {
    int t = tid + 256 * k;
    int ru = t / 68;
    int sub = t - ru * 68;
    int go = (ru >= 10) ? 1 : 0;
    int rr = ru - 10 * go;
    int s = sub >> 1, half = sub & 1;
    int h = h0 + rr, gw = w0g + s;
    go6[k] = go;
    vhw6[k] = (t < 1360) && ((unsigned)h < (unsigned)H_) &&
              ((unsigned)gw < (unsigned)W_);
    // [row][half][wslot 34][8ic] bf16 -> byte = ((rr*2 + half)*34 + s)*16
    ldsoB[k] = ((rr * 2 + half) * 34 + s) * 16;
    goffw[k] = half * 8 * DHW_ + h * W_ + gw;
  }
  const bool act5 = (tid < 80);   // k=5 task-active mask (k<5 always active)

  // Stage planes {g0, g0+1}: load + pack + write. Ring invariant: planes
  // 2dp-1..2dp+4 are 6 consecutive ints -> distinct mod 6, so write slots are
  // disjoint from every reader between consecutive barriers.
  auto stage_now = [&](int g0) {
    #pragma unroll
    for (int k = 0; k < 6; ++k) {
      int g = g0 + go6[k];
      bool v = vhw6[k] && ((unsigned)g < (unsigned)D_);
      unsigned offw = v ? (unsigned)(goffw[k] + g * HW_) : 0u;  // clamp: in-bounds
      float f[8];
      #pragma unroll
      for (int j = 0; j < 8; ++j) f[j] = xj[j][offw];
      uint4 val;
      val.x = v ? pack2(f[0], f[1]) : 0u;
      val.y = v ? pack2(f[2], f[3]) : 0u;
      val.z = v ? pack2(f[4], f[5]) : 0u;
      val.w = v ? pack2(f[6], f[7]) : 0u;
      if (k < 5 || act5)
        *(uint4*)((char*)xlds + (mod6(g + 6) * 10880 + ldsoB[k])) = val;
    }
  };

  const int dp0 = dphalf * 8;
  stage_now(2 * dp0 - 1);   // planes 2dp0-1, 2dp0
  stage_now(2 * dp0 + 1);   // planes 2dp0+1, 2dp0+2
  __syncthreads();          // prologue staging visible

  for (int dpi = 0; dpi < 8; ++dpi) {
    const int dp = dp0 + dpi;

    // ---- MFMA compute (operand-swapped: D rows = oc, cols = w) ---------------
    // b operands are register-resident: inner loop = a-frag ds_reads + MFMA.
    v16f acc[2][2];
    #pragma unroll
    for (int td = 0; td < 2; ++td)
      #pragma unroll
      for (int th = 0; th < 2; ++th)
        #pragma unroll
        for (int e = 0; e < 16; ++e) acc[td][th][e] = 0.f;

    int sj[4];
    #pragma unroll
    for (int j = 0; j < 4; ++j) sj[j] = mod6(2 * dp + 5 + j);   // (2dp-1+j) mod 6

    __builtin_amdgcn_s_setprio(1);
    #pragma unroll
    for (int kw = 0; kw < 3; ++kw) {
      frag a[4][4];   // patches [plane j = kd+td][row r = kh+th], rows 2q..2q+3
      #pragma unroll
      for (int j = 0; j < 4; ++j)
        #pragma unroll
        for (int r = 0; r < 4; ++r)
          a[j][r] = *(const frag*)
              &xlds[((sj[j] * 10 + 2 * q + r) * 2 + hs) * 272 + (kw + m) * 8];
      #pragma unroll
      for (int kd = 0; kd < 3; ++kd)
        #pragma unroll
        for (int kh = 0; kh < 3; ++kh) {
          #pragma unroll
          for (int td = 0; td < 2; ++td)
            #pragma unroll
            for (int th = 0; th < 2; ++th)
              acc[td][th] = __builtin_amdgcn_mfma_f32_32x32x16_bf16(
                  bw[(kd * 3 + kh) * 3 + kw], a[kd + td][kh + th],
                  acc[td][th], 0, 0, 0);
        }
    }
    __builtin_amdgcn_s_setprio(0);

    // Stage the next pair (planes 2dp+3, 2dp+4): slots disjoint from all
    // readers this side of the barrier (ring invariant above).
    if (dpi < 7) stage_now(2 * dp + 3);

    // ---- pool + bias + LSE(oc) + relu + store (all in-register) --------------
    // Pool d (td), h (th) in-register; w via DPP quad_perm [1,0,3,2] max.
    // LSE: no max-shift (|v| bounded, fp32 exp-sum safe); hs halves combined
    // with one shfl_xor(32). Independent of staging -> overlaps its latency.
    float Sh = 0.f;
    #pragma unroll
    for (int r = 0; r < 16; ++r) {
      float p = fmaxf(fmaxf(acc[0][0][r], acc[0][1][r]),
                      fmaxf(acc[1][0][r], acc[1][1][r]));
      int pi = __builtin_bit_cast(int, p);
      int qi = __builtin_amdgcn_update_dpp(pi, pi, 0xB1, 0xF, 0xF, false);
      float pw2 = fmaxf(p, __builtin_bit_cast(float, qi));
      Sh += __expf(pw2 + bias_r[r]);
    }
    float S = Sh + __shfl_xor(Sh, 32, 64);
    if (hs == 0 && (m & 1) == 0) {
      float r = fmaxf(__logf(S), 0.f);
      out[((n * 16 + dp) * 32 + 4 * hpt + q) * 32 + 16 * wtb + (m >> 1)] = r;
    }

    if (dpi < 7) __syncthreads();   // ONE barrier per dpi: commits visible
  }
}

extern "C" void kernel_launch(void* const* d_in, const int* in_sizes, int n_in,
                              void* d_out, int out_size, void* d_ws, size_t ws_size,
                              hipStream_t stream) {
  const float* x = (const float*)d_in[0];
  const float* w = (const float*)d_in[1];
  const float* b = (const float*)d_in[2];
  float* out = (float*)d_out;
  __hip_bfloat16* wt = (__hip_bfloat16*)d_ws;   // 27648 B
  wprep<<<dim3(54), dim3(256), 0, stream>>>(w, wt);
  conv_fused<<<dim3(2, 8, 32), dim3(256), 0, stream>>>(x, wt, b, out);
}